// Round 15
// baseline (114.349 us; speedup 1.0000x reference)
//
#include <hip/hip_runtime.h>
#include <math.h>

#define NW   12
#define DIM  4096
#define TPB  256

typedef float v2f __attribute__((ext_vector_type(2)));   // (re, im) -> v_pk_* f32

// DPP lane exchange (VALU, no LDS pipe).
// 0xB1=quad XOR1, 0x4E=quad XOR2, 0x1B=quad XOR3, 0x128=row_ror:8 (XOR8), 0x141=row_half_mirror (XOR7).
template<int CTRL>
__device__ __forceinline__ float fdpp(float v) {
    union { float f; int i; } u, w;
    u.f = v;
    w.i = __builtin_amdgcn_update_dpp(0, u.i, CTRL, 0xF, 0xF, false);
    return w.f;
}

// DPP with bound_ctrl=1 (invalid lanes read 0) — for shift-based reductions.
template<int CTRL>
__device__ __forceinline__ float fdpp0(float v) {
    union { float f; int i; } u, w;
    u.f = v;
    w.i = __builtin_amdgcn_update_dpp(0, u.i, CTRL, 0xF, 0xF, true);
    return w.f;
}

// Full-wave sum via fused v_add_dpp: row_shr 1/2/4/8 then row_bcast 15/31.
// Result lands in lane 63. Zero LDS-pipe traffic.
__device__ __forceinline__ float wave_red(float v) {
    v += fdpp0<0x111>(v);   // row_shr:1
    v += fdpp0<0x112>(v);   // row_shr:2
    v += fdpp0<0x114>(v);   // row_shr:4
    v += fdpp0<0x118>(v);   // row_shr:8  -> lane15 of each row = row sum
    v += fdpp0<0x142>(v);   // row_bcast:15
    v += fdpp0<0x143>(v);   // row_bcast:31 -> lane 63 = wave sum
    return v;
}

__device__ __forceinline__ v2f cmulq(v2f a, v2f b) {
    return (v2f){ fmaf(a.x, b.x, -a.y * b.y), fmaf(a.x, b.y, a.y * b.x) };
}

// RY on register bit B (0..3 of the 16-amp register file). Packed-f32 VALU.
template<int B>
__device__ __forceinline__ void ry_reg(v2f* r, float c, v2f vps, v2f vms) {
#pragma unroll
    for (int p = 0; p < 8; ++p) {
        const int i0 = ((p >> B) << (B + 1)) | (p & ((1 << B) - 1));
        const int i1 = i0 | (1 << B);
        const v2f a = r[i0], b = r[i1];
        r[i0] = __builtin_elementwise_fma(vms, b, a * c);   // c*a - s*b
        r[i1] = __builtin_elementwise_fma(vps, a, b * c);   // s*a + c*b
    }
}

// RY via single-DPP partner exchange on a lane bit.
template<int CTRL>
__device__ __forceinline__ void ry_dpp(v2f* r, float c, v2f vsp) {
#pragma unroll
    for (int k = 0; k < 16; ++k) {
        const v2f p = { fdpp<CTRL>(r[k].x), fdpp<CTRL>(r[k].y) };
        r[k] = __builtin_elementwise_fma(vsp, p, r[k] * c);
    }
}

// RY on lane bit 2 (XOR4): partner = half_mirror(quad_xor3(x)) -> x[l^7^3] = x[l^4].
__device__ __forceinline__ void ry_xor4(v2f* r, float c, v2f vsp) {
#pragma unroll
    for (int k = 0; k < 16; ++k) {
        const v2f p = { fdpp<0x141>(fdpp<0x1B>(r[k].x)),
                        fdpp<0x141>(fdpp<0x1B>(r[k].y)) };
        r[k] = __builtin_elementwise_fma(vsp, p, r[k] * c);
    }
}

// ---------------- pre-kernel: per-sample encoding angles -> ws[s*24 + {cos12,sin12}]
__global__ __launch_bounds__(256, 2)
void feat_kernel(const float* __restrict__ x, const float* __restrict__ W1,
                 const float* __restrict__ b1, float* __restrict__ ws) {
    const int lane = threadIdx.x & 63;
    const int s    = blockIdx.x * 4 + (threadIdx.x >> 6);   // one wave per sample
    const float4* xr = (const float4*)(x + (size_t)s * 784);
    float acc[NW];
#pragma unroll
    for (int w = 0; w < NW; ++w) acc[w] = 0.f;
#pragma unroll
    for (int i = 0; i < 3; ++i) {
        const int j = lane + 64 * i;
        const float4 xv = xr[j];
#pragma unroll
        for (int w = 0; w < NW; ++w) {
            const float4 wv = ((const float4*)(W1 + w * 784))[j];
            acc[w] = fmaf(xv.x, wv.x, fmaf(xv.y, wv.y, fmaf(xv.z, wv.z, fmaf(xv.w, wv.w, acc[w]))));
        }
    }
    if (lane < 4) {
        const int j = 192 + lane;                           // 196 float4 total
        const float4 xv = xr[j];
#pragma unroll
        for (int w = 0; w < NW; ++w) {
            const float4 wv = ((const float4*)(W1 + w * 784))[j];
            acc[w] = fmaf(xv.x, wv.x, fmaf(xv.y, wv.y, fmaf(xv.z, wv.z, fmaf(xv.w, wv.w, acc[w]))));
        }
    }
#pragma unroll
    for (int w = 0; w < NW; ++w) {
        const float v = wave_red(acc[w]);
        if (lane == 63) {
            const float a = tanhf(v + b1[w]) * 3.14159265358979323846f;
            const float h = 0.5f * a;
            ws[(size_t)s * 24 + w]      = cosf(h);
            ws[(size_t)s * 24 + 12 + w] = sinf(h);
        }
    }
}

template<bool PRE>
__global__ __launch_bounds__(TPB, 5)   // 5 blocks/CU: LDS 5x32KiB = 160KiB exact
void qmnist_kernel(const float* __restrict__ x,  const float* __restrict__ W1,
                   const float* __restrict__ b1, const float* __restrict__ ryp,
                   const float* __restrict__ rzp, const float* __restrict__ W2,
                   const float* __restrict__ b2, float* __restrict__ out,
                   const float* __restrict__ feats) {
    // Exactly 32 KiB LDS. Small arrays alias the front (state lives in
    // registers whenever they are live; barriers order every transition).
    __shared__ v2f psi[DIM];
    float* smf  = (float*)psi;
    float* wred = smf;        // 48 floats
    float* encc = smf + 48;   // 12
    float* encs = smf + 60;   // 12
    float* zfin = smf + 72;   // 12

    const int tid  = threadIdx.x;
    const int blk  = blockIdx.x;
    const int lane = tid & 63;
    const int wave = tid >> 6;

    // ---------------- phase 0: encoding angles
    if constexpr (PRE) {
        // precomputed by feat_kernel: ws[blk*24 + {cos12, sin12}] -> smf[48..71]
        if (tid < 24) smf[48 + tid] = feats[(size_t)blk * 24 + tid];
        __syncthreads();
    } else {
        float acc[NW];
#pragma unroll
        for (int w = 0; w < NW; ++w) acc[w] = 0.f;
        if (tid < 196) {                      // 784 = 196 float4
            const float4 xv = ((const float4*)(x + (size_t)blk * 784))[tid];
#pragma unroll
            for (int w = 0; w < NW; ++w) {
                const float4 wv = ((const float4*)(W1 + w * 784))[tid];
                acc[w] = fmaf(xv.x, wv.x, fmaf(xv.y, wv.y, fmaf(xv.z, wv.z, xv.w * wv.w)));
            }
        }
#pragma unroll
        for (int w = 0; w < NW; ++w) {
            const float v = wave_red(acc[w]);
            if (lane == 63) wred[wave * NW + w] = v;
        }
        __syncthreads();
        if (tid < NW) {
            float feat = wred[tid] + wred[NW + tid] + wred[2 * NW + tid] + wred[3 * NW + tid] + b1[tid];
            float a = tanhf(feat) * 3.14159265358979323846f;
            float h = 0.5f * a;
            encc[tid] = cosf(h);
            encs[tid] = sinf(h);
        }
        __syncthreads();
    }

    // ---------------- init product state into REGISTERS.
    // amp index y = (k<<8)|tid; bit b of y <-> wire (11-b). bits 0..7 = tid, 8..11 = k.
    float hi = 1.f;
#pragma unroll
    for (int b = 0; b < 8; ++b)
        hi *= ((tid >> b) & 1) ? encs[11 - b] : encc[11 - b];
    v2f r[16];
#pragma unroll
    for (int k = 0; k < 16; ++k) {
        float f = hi;
        f *= (k & 1) ? encs[3] : encc[3];
        f *= (k & 2) ? encs[2] : encc[2];
        f *= (k & 4) ? encs[1] : encc[1];
        f *= (k & 8) ? encs[0] : encc[0];
        r[k] = (v2f){ f, 0.f };
    }

    // ---------------- variational params.
    const float ry = ryp[0], rz = rzp[0];
    const float c = cosf(0.5f * ry), s = sinf(0.5f * ry);
    const v2f vps = {  s,  s };
    const v2f vms = { -s, -s };
    const int pcT = __popc(tid);
    // qv[j] = cis(rz*(pcT+j-6)), qp[j] = i*qv[j] — 2 sincos + complex recurrence
    v2f qv[5], qp[5];
    {
        float sb, cb; __sincosf(rz * (float)(pcT - 6), &sb, &cb);
        float sd, cd; __sincosf(rz, &sd, &cd);
        qv[0] = (v2f){ cb, sb };
        const v2f step = (v2f){ cd, sd };
#pragma unroll
        for (int j = 1; j < 5; ++j) qv[j] = cmulq(qv[j - 1], step);
#pragma unroll
        for (int j = 0; j < 5; ++j) qp[j] = (v2f){ -qv[j].y, qv[j].x };
    }

    const v2f vs0 = (lane & 1) ? vps : vms;   // position 0, XOR1  quad_perm
    const v2f vs1 = (lane & 2) ? vps : vms;   // position 1, XOR2  quad_perm
    const v2f vs2 = (lane & 4) ? vps : vms;   // position 2, XOR4  chained DPP
    const v2f vs3 = (lane & 8) ? vps : vms;   // position 3, XOR8  row_ror:8

    // ---- Storage maps compose per layer via same-slot writes:
    //  sigma_0 = id, sigma_1 = Gray (y^(y>>1)), sigma_2 = Gray^2 (y^(y>>2)).
    // Every access = one base VGPR ^ compile-time imm; slot low4 is rank-4 in
    // t0..t3 for all patterns (triangular forms) -> conflict-free b64.
    const int A    = (tid & 15) | ((tid & 240) << 4);  // L1-amp base: t0-3 | t4-7<<8
    const int gt   = tid ^ (tid >> 1);                 // Gray(tid), bit7 = t7
    const int GA1  = A ^ (A >> 1);                     // Gray(A)
    const int GA2  = A ^ (A >> 2);                     // Gray^2(A)
    const int bs2  = tid ^ (tid >> 2);                 // Gray^2(tid), bits 0-7

    // macros over compile-time k (all inside #pragma unroll loops)
#define GREG() { ry_reg<0>(r, c, vps, vms); ry_reg<1>(r, c, vps, vms); \
                 ry_reg<2>(r, c, vps, vms); ry_reg<3>(r, c, vps, vms); }
#define GDPP() { ry_dpp<0xB1>(r, c, vs0); ry_dpp<0x4E>(r, c, vs1); \
                 ry_xor4(r, c, vs2);      ry_dpp<0x128>(r, c, vs3); }
#define RZF()  _Pragma("unroll") for (int k = 0; k < 16; ++k) { \
                 const int j = __popc(k); \
                 r[k] = __builtin_elementwise_fma((v2f){ r[k].y, r[k].y }, qp[j], qv[j] * r[k].x); }
    // sigma-dependent addresses (k compile-time):
#define S0_Y(k)   (((k) << 8) | tid)                                     // sigma0(y)
#define S0_A(k)   (A | ((k) << 4))                                       // sigma0(L1 amp)
#define S1_Y(k)   ((gt ^ (((k) & 1) << 7)) | ((((k) ^ ((k) >> 1)) & 15) << 8))  // sigma1(y) = Gray(y)
#define S1_A(k)   (GA1 ^ (((k) << 4) ^ ((k) << 3)))                      // sigma1(L1 amp)
#define S2_Y(k)   (bs2 ^ (((k) & 3) << 6) ^ ((((k) ^ ((k) >> 2)) & 15) << 8))   // sigma2(y)
#define S2_A(k)   (GA2 ^ (((k) << 4) ^ ((k) << 2)))                      // sigma2(L1 amp)

    // ================ layer 0 (sigma = id) ================
    __syncthreads();                    // init's enc reads done before psi writes
    GREG();                             // positions 8-11
#pragma unroll
    for (int k = 0; k < 16; ++k) psi[S0_Y(k)] = r[k];        // PW1_0
    __syncthreads();
#pragma unroll
    for (int k = 0; k < 16; ++k) r[k] = psi[S0_A(k)];        // PR1_0 -> L1 layout
    GDPP();                             // positions 0-3 (overlap LDS latency)
    GREG();                             // positions 4-7
    RZF();
#pragma unroll
    for (int k = 0; k < 16; ++k) psi[S0_A(k)] = r[k];        // PW2_0 (same-slot)
    __syncthreads();
#pragma unroll
    for (int k = 0; k < 16; ++k) r[k] = psi[S1_Y(k)];        // PR2_0: amp Gray(y) @ sigma0

    // ================ layer 1 (sigma = Gray) — no loop-top barrier:
    // PW1_1 writes exactly the slots THIS thread read in PR2_0 (bijective
    // partition; in-thread order via the r[k] data dependency).
    GREG();
#pragma unroll
    for (int k = 0; k < 16; ++k) psi[S1_Y(k)] = r[k];        // PW1_1 -> sigma1
    __syncthreads();
#pragma unroll
    for (int k = 0; k < 16; ++k) r[k] = psi[S1_A(k)];        // PR1_1
    GDPP();
    GREG();
    RZF();
#pragma unroll
    for (int k = 0; k < 16; ++k) psi[S1_A(k)] = r[k];        // PW2_1 (same-slot)
    __syncthreads();
#pragma unroll
    for (int k = 0; k < 16; ++k) r[k] = psi[S2_Y(k)];        // PR2_1: amp Gray(y) @ sigma1

    // ================ layer 2 (sigma = Gray^2; RZ+CNOT folded into measure)
    GREG();
#pragma unroll
    for (int k = 0; k < 16; ++k) psi[S2_Y(k)] = r[k];        // PW1_2 -> sigma2
    __syncthreads();
#pragma unroll
    for (int k = 0; k < 16; ++k) r[k] = psi[S2_A(k)];        // PR1_2 -> L1 layout
    GDPP();
    GREG();
    __syncthreads();                    // all psi reads done before aliasing reuse

    // ---------------- measure <Z_w> with CNOT folded into signs.
    // State held: amp u = t0-3 | k<<4 | t4-7<<8 (pre-CNOT, phase-free modulus).
    // psi_post[v] = phi[v ^ (v>>1)]  =>  <Z_w> sign = parity(u >> (11-w)).
    float T = 0.f, Sp = 0.f, S1 = 0.f, S2 = 0.f, S3 = 0.f;
#pragma unroll
    for (int k = 0; k < 16; ++k) {
        const float pp = fmaf(r[k].x, r[k].x, r[k].y * r[k].y);
        T += pp;
        Sp += (__popc(k) & 1)        ? -pp : pp;   // parity(k)
        S1 += (__popc(k >> 1) & 1)   ? -pp : pp;   // parity(k>>1)
        S2 += (__popc(k >> 2) & 1)   ? -pp : pp;   // parity(k>>2)
        S3 += ((k >> 3) & 1)         ? -pp : pp;   // parity(k>>3)
    }
    const int t1 = (tid >> 1) & 1, t2 = (tid >> 2) & 1, t3 = (tid >> 3) & 1;
    const int t4 = (tid >> 4) & 1, t5 = (tid >> 5) & 1, t6 = (tid >> 6) & 1,
              t7 = (tid >> 7) & 1;
    const int p47 = t4 ^ t5 ^ t6 ^ t7;
    float contrib[NW];
    contrib[0]  = t7                   ? -T : T;    // b=11
    contrib[1]  = (t6 ^ t7)            ? -T : T;    // b=10
    contrib[2]  = (t5 ^ t6 ^ t7)       ? -T : T;    // b=9
    contrib[3]  = p47                  ? -T : T;    // b=8
    contrib[4]  = p47                  ? -S3 : S3;  // b=7
    contrib[5]  = p47                  ? -S2 : S2;  // b=6
    contrib[6]  = p47                  ? -S1 : S1;  // b=5
    contrib[7]  = p47                  ? -Sp : Sp;  // b=4
    contrib[8]  = (t3 ^ p47)           ? -Sp : Sp;  // b=3
    contrib[9]  = (t2 ^ t3 ^ p47)      ? -Sp : Sp;  // b=2
    contrib[10] = (t1 ^ t2 ^ t3 ^ p47) ? -Sp : Sp;  // b=1
    contrib[11] = (pcT & 1)            ? -Sp : Sp;  // b=0: parity(tid)
#pragma unroll
    for (int w = 0; w < NW; ++w) {
        const float v = wave_red(contrib[w]);
        if (lane == 63) wred[wave * NW + w] = v;
    }
    __syncthreads();
    if (tid < NW)
        zfin[tid] = wred[tid] + wred[NW + tid] + wred[2 * NW + tid] + wred[3 * NW + tid];
    __syncthreads();

    // ---------------- head: out = z @ W2^T + b2
    if (tid < 10) {
        float o = b2[tid];
#pragma unroll
        for (int w = 0; w < NW; ++w)
            o = fmaf(zfin[w], W2[tid * NW + w], o);
        out[(size_t)blk * 10 + tid] = o;
    }
}

extern "C" void kernel_launch(void* const* d_in, const int* in_sizes, int n_in,
                              void* d_out, int out_size, void* d_ws, size_t ws_size,
                              hipStream_t stream) {
    const float* x   = (const float*)d_in[0];
    const float* W1  = (const float*)d_in[1];
    const float* b1  = (const float*)d_in[2];
    const float* ry  = (const float*)d_in[3];
    const float* rz  = (const float*)d_in[4];
    const float* W2  = (const float*)d_in[5];
    const float* b2  = (const float*)d_in[6];
    float* out = (float*)d_out;

    const int batch = in_sizes[0] / 784;   // 2048
    if (d_ws != nullptr && ws_size >= (size_t)batch * 24 * sizeof(float)) {
        feat_kernel<<<batch / 4, 256, 0, stream>>>(x, W1, b1, (float*)d_ws);
        qmnist_kernel<true><<<batch, TPB, 0, stream>>>(x, W1, b1, ry, rz, W2, b2, out,
                                                       (const float*)d_ws);
    } else {
        qmnist_kernel<false><<<batch, TPB, 0, stream>>>(x, W1, b1, ry, rz, W2, b2, out,
                                                        nullptr);
    }
}

// Round 16
// 108.796 us; speedup vs baseline: 1.0510x; 1.0510x over previous
//
#include <hip/hip_runtime.h>
#include <math.h>

#define NW   12
#define DIM  4096
#define TPB  256

typedef float v2f __attribute__((ext_vector_type(2)));   // (re, im) -> v_pk_* f32

// DPP lane exchange (VALU, no LDS pipe).
// 0xB1=quad XOR1, 0x4E=quad XOR2, 0x1B=quad XOR3, 0x128=row_ror:8 (XOR8), 0x141=row_half_mirror (XOR7).
template<int CTRL>
__device__ __forceinline__ float fdpp(float v) {
    union { float f; int i; } u, w;
    u.f = v;
    w.i = __builtin_amdgcn_update_dpp(0, u.i, CTRL, 0xF, 0xF, false);
    return w.f;
}

// DPP with bound_ctrl=1 (invalid lanes read 0) — for shift-based reductions.
template<int CTRL>
__device__ __forceinline__ float fdpp0(float v) {
    union { float f; int i; } u, w;
    u.f = v;
    w.i = __builtin_amdgcn_update_dpp(0, u.i, CTRL, 0xF, 0xF, true);
    return w.f;
}

// Full-wave sum via fused v_add_dpp: row_shr 1/2/4/8 then row_bcast 15/31.
// Result lands in lane 63. Zero LDS-pipe traffic.
__device__ __forceinline__ float wave_red(float v) {
    v += fdpp0<0x111>(v);   // row_shr:1
    v += fdpp0<0x112>(v);   // row_shr:2
    v += fdpp0<0x114>(v);   // row_shr:4
    v += fdpp0<0x118>(v);   // row_shr:8  -> lane15 of each row = row sum
    v += fdpp0<0x142>(v);   // row_bcast:15
    v += fdpp0<0x143>(v);   // row_bcast:31 -> lane 63 = wave sum
    return v;
}

__device__ __forceinline__ v2f cmulq(v2f a, v2f b) {
    return (v2f){ fmaf(a.x, b.x, -a.y * b.y), fmaf(a.x, b.y, a.y * b.x) };
}

// RY on register bit B (0..3 of the 16-amp register file). Packed-f32 VALU.
template<int B>
__device__ __forceinline__ void ry_reg(v2f* r, float c, v2f vps, v2f vms) {
#pragma unroll
    for (int p = 0; p < 8; ++p) {
        const int i0 = ((p >> B) << (B + 1)) | (p & ((1 << B) - 1));
        const int i1 = i0 | (1 << B);
        const v2f a = r[i0], b = r[i1];
        r[i0] = __builtin_elementwise_fma(vms, b, a * c);   // c*a - s*b
        r[i1] = __builtin_elementwise_fma(vps, a, b * c);   // s*a + c*b
    }
}

// RY via single-DPP partner exchange on a lane bit.
template<int CTRL>
__device__ __forceinline__ void ry_dpp(v2f* r, float c, v2f vsp) {
#pragma unroll
    for (int k = 0; k < 16; ++k) {
        const v2f p = { fdpp<CTRL>(r[k].x), fdpp<CTRL>(r[k].y) };
        r[k] = __builtin_elementwise_fma(vsp, p, r[k] * c);
    }
}

// RY on lane bit 2 (XOR4): partner = half_mirror(quad_xor3(x)) -> x[l^7^3] = x[l^4].
__device__ __forceinline__ void ry_xor4(v2f* r, float c, v2f vsp) {
#pragma unroll
    for (int k = 0; k < 16; ++k) {
        const v2f p = { fdpp<0x141>(fdpp<0x1B>(r[k].x)),
                        fdpp<0x141>(fdpp<0x1B>(r[k].y)) };
        r[k] = __builtin_elementwise_fma(vsp, p, r[k] * c);
    }
}

__global__ __launch_bounds__(TPB, 5)   // 5 blocks/CU: LDS 5x32KiB = 160KiB exact
void qmnist_kernel(const float* __restrict__ x,  const float* __restrict__ W1,
                   const float* __restrict__ b1, const float* __restrict__ ryp,
                   const float* __restrict__ rzp, const float* __restrict__ W2,
                   const float* __restrict__ b2, float* __restrict__ out) {
    // Exactly 32 KiB LDS. Small arrays alias the front (state lives in
    // registers whenever they are live; barriers order every transition).
    __shared__ v2f psi[DIM];
    float* smf  = (float*)psi;
    float* wred = smf;        // 48 floats
    float* encc = smf + 48;   // 12
    float* encs = smf + 60;   // 12
    float* zfin = smf + 72;   // 12

    const int tid  = threadIdx.x;
    const int blk  = blockIdx.x;
    const int lane = tid & 63;
    const int wave = tid >> 6;

    // ---------------- phase 0 (wave-per-wires): wave v computes wires 3v..3v+2
    // over ALL 784 elems of x[blk]. All 256 threads active, 3 wave_reds (not
    // 12), no cross-wave wred stage, ONE barrier (was two).
    {
        const int w0 = wave * 3;
        const float4* xr  = (const float4*)(x + (size_t)blk * 784);
        const float4* w1a = (const float4*)(W1 + (size_t)(w0 + 0) * 784);
        const float4* w1b = (const float4*)(W1 + (size_t)(w0 + 1) * 784);
        const float4* w1c = (const float4*)(W1 + (size_t)(w0 + 2) * 784);
        float a0 = 0.f, a1 = 0.f, a2 = 0.f;
#pragma unroll
        for (int i = 0; i < 4; ++i) {
            const int j = lane + 64 * i;          // 196 float4 total
            if (i < 3 || lane < 4) {
                const float4 xv = xr[j];
                const float4 r0 = w1a[j], r1 = w1b[j], r2 = w1c[j];
                a0 = fmaf(xv.x, r0.x, fmaf(xv.y, r0.y, fmaf(xv.z, r0.z, fmaf(xv.w, r0.w, a0))));
                a1 = fmaf(xv.x, r1.x, fmaf(xv.y, r1.y, fmaf(xv.z, r1.z, fmaf(xv.w, r1.w, a1))));
                a2 = fmaf(xv.x, r2.x, fmaf(xv.y, r2.y, fmaf(xv.z, r2.z, fmaf(xv.w, r2.w, a2))));
            }
        }
        a0 = wave_red(a0); a1 = wave_red(a1); a2 = wave_red(a2);
        if (lane == 63) {
            const float f[3] = { a0, a1, a2 };
#pragma unroll
            for (int d = 0; d < 3; ++d) {
                const float a = tanhf(f[d] + b1[w0 + d]) * 3.14159265358979323846f;
                const float h = 0.5f * a;
                encc[w0 + d] = cosf(h);
                encs[w0 + d] = sinf(h);
            }
        }
    }
    __syncthreads();

    // ---------------- init product state into REGISTERS.
    // amp index y = (k<<8)|tid; bit b of y <-> wire (11-b). bits 0..7 = tid, 8..11 = k.
    float hi = 1.f;
#pragma unroll
    for (int b = 0; b < 8; ++b)
        hi *= ((tid >> b) & 1) ? encs[11 - b] : encc[11 - b];
    v2f r[16];
#pragma unroll
    for (int k = 0; k < 16; ++k) {
        float f = hi;
        f *= (k & 1) ? encs[3] : encc[3];
        f *= (k & 2) ? encs[2] : encc[2];
        f *= (k & 4) ? encs[1] : encc[1];
        f *= (k & 8) ? encs[0] : encc[0];
        r[k] = (v2f){ f, 0.f };
    }

    // ---------------- variational params.
    const float ry = ryp[0], rz = rzp[0];
    const float c = cosf(0.5f * ry), s = sinf(0.5f * ry);
    const v2f vps = {  s,  s };
    const v2f vms = { -s, -s };
    const int pcT = __popc(tid);
    // qv[j] = cis(rz*(pcT+j-6)), qp[j] = i*qv[j] — 2 sincos + complex recurrence
    v2f qv[5], qp[5];
    {
        float sb, cb; __sincosf(rz * (float)(pcT - 6), &sb, &cb);
        float sd, cd; __sincosf(rz, &sd, &cd);
        qv[0] = (v2f){ cb, sb };
        const v2f step = (v2f){ cd, sd };
#pragma unroll
        for (int j = 1; j < 5; ++j) qv[j] = cmulq(qv[j - 1], step);
#pragma unroll
        for (int j = 0; j < 5; ++j) qp[j] = (v2f){ -qv[j].y, qv[j].x };
    }

    const v2f vs0 = (lane & 1) ? vps : vms;   // position 0, XOR1  quad_perm
    const v2f vs1 = (lane & 2) ? vps : vms;   // position 1, XOR2  quad_perm
    const v2f vs2 = (lane & 4) ? vps : vms;   // position 2, XOR4  chained DPP
    const v2f vs3 = (lane & 8) ? vps : vms;   // position 3, XOR8  row_ror:8

    // ---- Storage maps compose per layer via same-slot writes:
    //  sigma_0 = id, sigma_1 = Gray (y^(y>>1)), sigma_2 = Gray^2 (y^(y>>2)).
    // Every access = one base VGPR ^ compile-time imm; slot low4 is rank-4 in
    // t0..t3 for all patterns (triangular forms) -> conflict-free b64.
    const int A    = (tid & 15) | ((tid & 240) << 4);  // L1-amp base: t0-3 | t4-7<<8
    const int gt   = tid ^ (tid >> 1);                 // Gray(tid), bit7 = t7
    const int GA1  = A ^ (A >> 1);                     // Gray(A)
    const int GA2  = A ^ (A >> 2);                     // Gray^2(A)
    const int bs2  = tid ^ (tid >> 2);                 // Gray^2(tid), bits 0-7

    // macros over compile-time k (all inside #pragma unroll loops)
#define GREG() { ry_reg<0>(r, c, vps, vms); ry_reg<1>(r, c, vps, vms); \
                 ry_reg<2>(r, c, vps, vms); ry_reg<3>(r, c, vps, vms); }
#define GDPP() { ry_dpp<0xB1>(r, c, vs0); ry_dpp<0x4E>(r, c, vs1); \
                 ry_xor4(r, c, vs2);      ry_dpp<0x128>(r, c, vs3); }
#define RZF()  _Pragma("unroll") for (int k = 0; k < 16; ++k) { \
                 const int j = __popc(k); \
                 r[k] = __builtin_elementwise_fma((v2f){ r[k].y, r[k].y }, qp[j], qv[j] * r[k].x); }
    // sigma-dependent addresses (k compile-time):
#define S0_Y(k)   (((k) << 8) | tid)                                     // sigma0(y)
#define S0_A(k)   (A | ((k) << 4))                                       // sigma0(L1 amp)
#define S1_Y(k)   ((gt ^ (((k) & 1) << 7)) | ((((k) ^ ((k) >> 1)) & 15) << 8))  // sigma1(y) = Gray(y)
#define S1_A(k)   (GA1 ^ (((k) << 4) ^ ((k) << 3)))                      // sigma1(L1 amp)
#define S2_Y(k)   (bs2 ^ (((k) & 3) << 6) ^ ((((k) ^ ((k) >> 2)) & 15) << 8))   // sigma2(y)
#define S2_A(k)   (GA2 ^ (((k) << 4) ^ ((k) << 2)))                      // sigma2(L1 amp)

    // ================ layer 0 (sigma = id) ================
    GREG();                             // positions 8-11
#pragma unroll
    for (int k = 0; k < 16; ++k) psi[S0_Y(k)] = r[k];        // PW1_0
    __syncthreads();
#pragma unroll
    for (int k = 0; k < 16; ++k) r[k] = psi[S0_A(k)];        // PR1_0 -> L1 layout
    GDPP();                             // positions 0-3 (overlap LDS latency)
    GREG();                             // positions 4-7
    RZF();
#pragma unroll
    for (int k = 0; k < 16; ++k) psi[S0_A(k)] = r[k];        // PW2_0 (same-slot)
    __syncthreads();
#pragma unroll
    for (int k = 0; k < 16; ++k) r[k] = psi[S1_Y(k)];        // PR2_0: amp Gray(y) @ sigma0

    // ================ layer 1 (sigma = Gray) — no loop-top barrier:
    // PW1_1 writes exactly the slots THIS thread read in PR2_0 (bijective
    // partition; in-thread order via the r[k] data dependency).
    GREG();
#pragma unroll
    for (int k = 0; k < 16; ++k) psi[S1_Y(k)] = r[k];        // PW1_1 -> sigma1
    __syncthreads();
#pragma unroll
    for (int k = 0; k < 16; ++k) r[k] = psi[S1_A(k)];        // PR1_1
    GDPP();
    GREG();
    RZF();
#pragma unroll
    for (int k = 0; k < 16; ++k) psi[S1_A(k)] = r[k];        // PW2_1 (same-slot)
    __syncthreads();
#pragma unroll
    for (int k = 0; k < 16; ++k) r[k] = psi[S2_Y(k)];        // PR2_1: amp Gray(y) @ sigma1

    // ================ layer 2 (sigma = Gray^2; RZ+CNOT folded into measure)
    GREG();
#pragma unroll
    for (int k = 0; k < 16; ++k) psi[S2_Y(k)] = r[k];        // PW1_2 -> sigma2
    __syncthreads();
#pragma unroll
    for (int k = 0; k < 16; ++k) r[k] = psi[S2_A(k)];        // PR1_2 -> L1 layout
    GDPP();
    GREG();
    __syncthreads();                    // all psi reads done before aliasing reuse

    // ---------------- measure <Z_w> with CNOT folded into signs.
    // State held: amp u = t0-3 | k<<4 | t4-7<<8 (pre-CNOT, phase-free modulus).
    // psi_post[v] = phi[v ^ (v>>1)]  =>  <Z_w> sign = parity(u >> (11-w)).
    float T = 0.f, Sp = 0.f, S1 = 0.f, S2 = 0.f, S3 = 0.f;
#pragma unroll
    for (int k = 0; k < 16; ++k) {
        const float pp = fmaf(r[k].x, r[k].x, r[k].y * r[k].y);
        T += pp;
        Sp += (__popc(k) & 1)        ? -pp : pp;   // parity(k)
        S1 += (__popc(k >> 1) & 1)   ? -pp : pp;   // parity(k>>1)
        S2 += (__popc(k >> 2) & 1)   ? -pp : pp;   // parity(k>>2)
        S3 += ((k >> 3) & 1)         ? -pp : pp;   // parity(k>>3)
    }
    const int t1 = (tid >> 1) & 1, t2 = (tid >> 2) & 1, t3 = (tid >> 3) & 1;
    const int t4 = (tid >> 4) & 1, t5 = (tid >> 5) & 1, t6 = (tid >> 6) & 1,
              t7 = (tid >> 7) & 1;
    const int p47 = t4 ^ t5 ^ t6 ^ t7;
    float contrib[NW];
    contrib[0]  = t7                   ? -T : T;    // b=11
    contrib[1]  = (t6 ^ t7)            ? -T : T;    // b=10
    contrib[2]  = (t5 ^ t6 ^ t7)       ? -T : T;    // b=9
    contrib[3]  = p47                  ? -T : T;    // b=8
    contrib[4]  = p47                  ? -S3 : S3;  // b=7
    contrib[5]  = p47                  ? -S2 : S2;  // b=6
    contrib[6]  = p47                  ? -S1 : S1;  // b=5
    contrib[7]  = p47                  ? -Sp : Sp;  // b=4
    contrib[8]  = (t3 ^ p47)           ? -Sp : Sp;  // b=3
    contrib[9]  = (t2 ^ t3 ^ p47)      ? -Sp : Sp;  // b=2
    contrib[10] = (t1 ^ t2 ^ t3 ^ p47) ? -Sp : Sp;  // b=1
    contrib[11] = (pcT & 1)            ? -Sp : Sp;  // b=0: parity(tid)
#pragma unroll
    for (int w = 0; w < NW; ++w) {
        const float v = wave_red(contrib[w]);
        if (lane == 63) wred[wave * NW + w] = v;
    }
    __syncthreads();
    if (tid < NW)
        zfin[tid] = wred[tid] + wred[NW + tid] + wred[2 * NW + tid] + wred[3 * NW + tid];
    __syncthreads();

    // ---------------- head: out = z @ W2^T + b2
    if (tid < 10) {
        float o = b2[tid];
#pragma unroll
        for (int w = 0; w < NW; ++w)
            o = fmaf(zfin[w], W2[tid * NW + w], o);
        out[(size_t)blk * 10 + tid] = o;
    }
}

extern "C" void kernel_launch(void* const* d_in, const int* in_sizes, int n_in,
                              void* d_out, int out_size, void* d_ws, size_t ws_size,
                              hipStream_t stream) {
    const float* x   = (const float*)d_in[0];
    const float* W1  = (const float*)d_in[1];
    const float* b1  = (const float*)d_in[2];
    const float* ry  = (const float*)d_in[3];
    const float* rz  = (const float*)d_in[4];
    const float* W2  = (const float*)d_in[5];
    const float* b2  = (const float*)d_in[6];
    float* out = (float*)d_out;

    const int batch = in_sizes[0] / 784;   // 2048
    qmnist_kernel<<<batch, TPB, 0, stream>>>(x, W1, b1, ry, rz, W2, b2, out);
}